// Round 17
// baseline (16.197 us; speedup 1.0000x reference)
//
#include <hip/hip_runtime.h>
#include <hip/hip_bf16.h>

#define B 8
#define N 4096
#define BN (B * N)            // 32768 nodes
#define NBLK_MIN 1024         // 8 b x 16 qb(256q) x 8 cc(512c)
#define NBLK_LOSS 128

typedef __attribute__((ext_vector_type(4)))  float f32x4;
typedef __attribute__((ext_vector_type(16))) float f32x16;
typedef __attribute__((ext_vector_type(8)))  short bf16x8;

__device__ __forceinline__ unsigned short f2bf(float x) {
    __hip_bfloat16 h = __float2bfloat16(x);
    return *reinterpret_cast<unsigned short*>(&h);
}
__device__ __forceinline__ float bf2f(unsigned short u) {
    __hip_bfloat16 h;
    *reinterpret_cast<unsigned short*>(&h) = u;
    return __bfloat162float(h);
}

// ---------------- k_min: 32x32x16-MFMA all-pairs partial min ----------------
// EXACT R15 body (verified absmax=0) + ONLY ONE change:
// __launch_bounds__(256, 4) -> (256, 3): VGPR cap 128 -> ~170.
// R15 decomposition: geometry cost +0.4 us (R8 vs R9 calibration), cap-128
// cost +0.75 us (spills). Cap-170 should be spill-free while still allowing
// 3 blocks/CU = 3 waves/SIMD (grid 1024 = 4 blocks/CU available).
// Block (256 thr = 4 waves) = 256 queries x 512 candidates.
// A-frag: row=l&31 (cand), k=(l>>5)*8+j. B-frag: col=l&31 (query), same k.
// C/D: col=l&31, row=(reg&3)+8*(reg>>2)+4*(l>>5) [m74/m101 + R8-verified].
// v = -2 q.c + |c|^2; |q|^2 added in fp32 at loss time.
__global__ __launch_bounds__(256, 3) void k_min(const float* __restrict__ c,
                                                float* __restrict__ wpart) {
    __shared__ unsigned short A[8192];        // 16 tiles x 1024 B = 16 KB

    int blk = blockIdx.x;
    int cc  = blk & 7;            // candidate chunk (512)
    int qb  = (blk >> 3) & 15;    // query block (256)
    int b   = blk >> 7;           // batch

    int t = threadIdx.x;
    int l = t & 63;
    int w = __builtin_amdgcn_readfirstlane(t >> 6);

    const float* cb = c + (size_t)b * N * 3;
    int C0  = cc << 9;
    int Q0w = (qb << 8) + (w << 6);           // this wave's first query (64 q)

    // ---- stage: thread t converts cands 2t, 2t+1 (3 coalesced float2) ----
    // (R6-verified unpack: candA=(e0.x,e0.y,e1.x), candB=(e1.y,e2.x,e2.y))
    {
        const float2* g2 = (const float2*)(cb + 3 * C0) + 3 * t;
        float2 e0 = g2[0], e1 = g2[1], e2 = g2[2];
        float cx[2] = {e0.x, e1.y};
        float cy[2] = {e0.y, e2.x};
        float cz[2] = {e1.x, e2.y};
        #pragma unroll
        for (int j = 0; j < 2; ++j) {
            float x = cx[j], y = cy[j], z = cz[j];
            float m2x = -2.f * x, m2y = -2.f * y, m2z = -2.f * z;
            unsigned short Hx = f2bf(m2x), Hy = f2bf(m2y), Hz = f2bf(m2z);
            unsigned short Lx = f2bf(m2x - bf2f(Hx));
            unsigned short Ly = f2bf(m2y - bf2f(Hy));
            unsigned short Lz = f2bf(m2z - bf2f(Hz));
            float nc = fmaf(z, z, fmaf(y, y, x * x));
            unsigned short nh = f2bf(nc);
            unsigned short nl = f2bf(nc - bf2f(nh));
            int cl   = 2 * t + j;
            int base = ((cl >> 5) << 9) + ((cl & 31) << 3);
            *(bf16x8*)(A + base) =
                (bf16x8){(short)Hx, (short)Hy, (short)Hz, (short)Lx,
                         (short)Ly, (short)Lz, (short)Hx, (short)Hy};
            *(bf16x8*)(A + base + 256) =
                (bf16x8){(short)Hz, (short)nh, (short)nl, 0, 0, 0, 0, 0};
        }
    }

    // ---- build 2 query B-frags (held in VGPRs all loop) ----
    bf16x8 bf0, bf1;
    {
        int qn = l & 31;
        const float* pa = cb + 3 * (Q0w + qn);
        const float* pb = cb + 3 * (Q0w + 32 + qn);
        float ax = pa[0], ay = pa[1], az = pa[2];
        float bx = pb[0], by = pb[1], bz = pb[2];
        const short one = (short)0x3F80;      // bf16(1.0)
        if (l < 32) {                         // k-slots 0..7
            unsigned short hx = f2bf(ax), hy = f2bf(ay), hz = f2bf(az);
            unsigned short lx = f2bf(ax - bf2f(hx));
            unsigned short ly = f2bf(ay - bf2f(hy));
            bf0 = (bf16x8){(short)hx, (short)hy, (short)hz, (short)hx,
                           (short)hy, (short)hz, (short)lx, (short)ly};
            hx = f2bf(bx); hy = f2bf(by); hz = f2bf(bz);
            lx = f2bf(bx - bf2f(hx)); ly = f2bf(by - bf2f(hy));
            bf1 = (bf16x8){(short)hx, (short)hy, (short)hz, (short)hx,
                           (short)hy, (short)hz, (short)lx, (short)ly};
        } else {                              // k-slots 8..15
            unsigned short hz = f2bf(az);
            unsigned short lz = f2bf(az - bf2f(hz));
            bf0 = (bf16x8){(short)lz, one, one, 0, 0, 0, 0, 0};
            hz = f2bf(bz); lz = f2bf(bz - bf2f(hz));
            bf1 = (bf16x8){(short)lz, one, one, 0, 0, 0, 0, 0};
        }
    }

    // diag bookkeeping: per frag the diag tile is wave-uniform
    int rel0 = Q0w - C0;
    int dt0  = ((unsigned)rel0 < 512u) ? (rel0 >> 5) : -1;
    int rel1 = rel0 + 32;
    int dt1  = ((unsigned)rel1 < 512u) ? (rel1 >> 5) : -1;
    // self-hit: query col rq = l&31 lives at row rq -> lane half (rq>>2)&1
    bool sel  = (((l >> 2) & 1) == (l >> 5));
    int  rsel = (l & 3) | (((l & 31) >> 3) << 2);

    __syncthreads();

    const float INF = __uint_as_float(0x7F800000u);
    float mm0[8], mm1[8];
    #pragma unroll
    for (int i = 0; i < 8; ++i) { mm0[i] = INF; mm1[i] = INF; }
    f32x16 z16 = {0.f, 0.f, 0.f, 0.f, 0.f, 0.f, 0.f, 0.f,
                  0.f, 0.f, 0.f, 0.f, 0.f, 0.f, 0.f, 0.f};

    #pragma unroll 2
    for (int tile = 0; tile < 16; ++tile) {
        bf16x8 a = *(const bf16x8*)(A + (tile << 9) + l * 8);
        f32x16 d0 = __builtin_amdgcn_mfma_f32_32x32x16_bf16(a, bf0, z16, 0, 0, 0);
        if (tile == dt0) {
            #pragma unroll
            for (int i = 0; i < 16; ++i)
                d0[i] = (sel && rsel == i) ? INF : d0[i];
        }
        #pragma unroll
        for (int i = 0; i < 8; ++i)
            mm0[i] = fminf(fminf(mm0[i], d0[2 * i]), d0[2 * i + 1]);

        f32x16 d1 = __builtin_amdgcn_mfma_f32_32x32x16_bf16(a, bf1, z16, 0, 0, 0);
        if (tile == dt1) {
            #pragma unroll
            for (int i = 0; i < 16; ++i)
                d1[i] = (sel && rsel == i) ? INF : d1[i];
        }
        #pragma unroll
        for (int i = 0; i < 8; ++i)
            mm1[i] = fminf(fminf(mm1[i], d1[2 * i]), d1[2 * i + 1]);
    }

    // ---- fold 8 -> 1 per frag, then combine row-halves (xor 32) ----
    float M0 = fminf(fminf(fminf(mm0[0], mm0[1]), fminf(mm0[2], mm0[3])),
                     fminf(fminf(mm0[4], mm0[5]), fminf(mm0[6], mm0[7])));
    float M1 = fminf(fminf(fminf(mm1[0], mm1[1]), fminf(mm1[2], mm1[3])),
                     fminf(fminf(mm1[4], mm1[5]), fminf(mm1[6], mm1[7])));
    M0 = fminf(M0, __shfl_xor(M0, 32));
    M1 = fminf(M1, __shfl_xor(M1, 32));

    // lane l stores query Q0w + l (lanes<32 from frag0, >=32 from frag1)
    float val = (l < 32) ? M0 : M1;
    wpart[(size_t)((b << 12) + Q0w + l) * 8 + cc] = val;
}

// ---------------- loss stage 1: 128 block partials (no atomics) -------------
__global__ __launch_bounds__(256) void k_loss1(const float* __restrict__ c,
                                               const float* __restrict__ wpart,
                                               double* __restrict__ partials) {
    int t = threadIdx.x;
    int i = blockIdx.x * 256 + t;             // global node index
    const float4* wp = (const float4*)(wpart + (size_t)i * 8);
    float4 v0 = wp[0], v1 = wp[1];
    float m = fminf(fminf(fminf(v0.x, v0.y), fminf(v0.z, v0.w)),
                    fminf(fminf(v1.x, v1.y), fminf(v1.z, v1.w)));

    float x = c[3 * i], y = c[3 * i + 1], z = c[3 * i + 2];
    float nrm = fmaf(z, z, fmaf(y, y, x * x));   // |q|^2 in fp32
    float d2 = fmaxf(m + nrm, 0.0f);
    float e  = sqrtf(d2) - 0.2f;
    double s = (double)(e * e);

    for (int off = 32; off; off >>= 1) s += __shfl_down(s, off);
    __shared__ double sh[4];
    int wv = t >> 6, l = t & 63;
    if (l == 0) sh[wv] = s;
    __syncthreads();
    if (t == 0) partials[blockIdx.x] = sh[0] + sh[1] + sh[2] + sh[3];
}

// ---------------- loss stage 2: fold 128 partials -> scalar -----------------
__global__ __launch_bounds__(128) void k_loss2(const double* __restrict__ partials,
                                               float* __restrict__ out) {
    int t = threadIdx.x;
    double s = partials[t];
    for (int off = 32; off; off >>= 1) s += __shfl_down(s, off);
    __shared__ double sh[2];
    if ((t & 63) == 0) sh[t >> 6] = s;
    __syncthreads();
    if (t == 0) out[0] = (float)((sh[0] + sh[1]) / (double)BN);
}

// ---------------- fallback (tiny workspace): fused single kernel ------------
__global__ __launch_bounds__(64) void k_single(const float* __restrict__ c,
                                               float* __restrict__ out) {
    __shared__ float sx[N], sy[N], sz[N];
    int blk = blockIdx.x;
    int qt  = blk & (N / 64 - 1);
    int b   = blk / (N / 64);
    const float* cb = c + (size_t)b * N * 3;
    int t = threadIdx.x;

    for (int k = t; k < N; k += 64) {
        sx[k] = cb[3 * k];
        sy[k] = cb[3 * k + 1];
        sz[k] = cb[3 * k + 2];
    }
    __syncthreads();

    int   qi = qt * 64 + t;
    float qx = sx[qi], qy = sy[qi], qz = sz[qi];
    const float INF = __uint_as_float(0x7F800000u);
    float m0 = INF, m1 = INF;
    for (int k = 0; k < N; k += 2) {
        float dx0 = qx - sx[k],     dy0 = qy - sy[k],     dz0 = qz - sz[k];
        float dx1 = qx - sx[k + 1], dy1 = qy - sy[k + 1], dz1 = qz - sz[k + 1];
        float d0 = dx0 * dx0 + dy0 * dy0 + dz0 * dz0;
        float d1 = dx1 * dx1 + dy1 * dy1 + dz1 * dz1;
        d0 = (k + 0 == qi) ? INF : d0;
        d1 = (k + 1 == qi) ? INF : d1;
        m0 = fminf(m0, d0);
        m1 = fminf(m1, d1);
    }
    float e = sqrtf(fminf(m0, m1)) - 0.2f;
    float v = e * e;
    for (int off = 32; off; off >>= 1) v += __shfl_down(v, off);
    if (t == 0) atomicAdd(out, v / (float)BN);
}

extern "C" void kernel_launch(void* const* d_in, const int* in_sizes, int n_in,
                              void* d_out, int out_size, void* d_ws, size_t ws_size,
                              hipStream_t stream) {
    const float* c   = (const float*)d_in[0];
    float*       out = (float*)d_out;

    const size_t off_part = (size_t)BN * 8 * sizeof(float);   // 1 MB
    const size_t need     = off_part + NBLK_LOSS * sizeof(double);
    if (ws_size >= need) {
        float*  wpart    = (float*)d_ws;
        double* partials = (double*)((char*)d_ws + off_part);
        k_min  <<<NBLK_MIN, 256, 0, stream>>>(c, wpart);
        k_loss1<<<NBLK_LOSS, 256, 0, stream>>>(c, wpart, partials);
        k_loss2<<<1, 128, 0, stream>>>(partials, out);
    } else {
        hipMemsetAsync(d_out, 0, sizeof(float), stream);
        k_single<<<B * (N / 64), 64, 0, stream>>>(c, out);
    }
}

// Round 18
// 14.916 us; speedup vs baseline: 1.0858x; 1.0858x over previous
//
#include <hip/hip_runtime.h>
#include <hip/hip_bf16.h>

#define B 8
#define N 4096
#define BN (B * N)            // 32768 nodes
#define NBLK_MIN 512          // 8 b x 16 qb(256q) x 4 cc(1024c)
#define NBLK_LOSS 128

typedef __attribute__((ext_vector_type(4)))  float f32x4;
typedef __attribute__((ext_vector_type(16))) float f32x16;
typedef __attribute__((ext_vector_type(8)))  short bf16x8;

__device__ __forceinline__ unsigned short f2bf(float x) {
    __hip_bfloat16 h = __float2bfloat16(x);
    return *reinterpret_cast<unsigned short*>(&h);
}
__device__ __forceinline__ float bf2f(unsigned short u) {
    __hip_bfloat16 h;
    *reinterpret_cast<unsigned short*>(&h) = u;
    return __bfloat162float(h);
}

// ---------------- k_min: 32x32x16-MFMA all-pairs partial min ----------------
// R14 EXACT (best measured: 14.98 us, absmax=0). Occupancy ladder mapped:
// 1 wave/SIMD (R13) 17.6 | 2 (this) 14.98 | 3 (R16) 16.2 | 4 (R15) 16.1.
// Block (256 thr = 4 waves) = 256 queries x 1024 candidates,
// __launch_bounds__(256,2) -> 2 blocks/CU = 2 waves/SIMD (the binding fix).
// A-frag: row=l&31 (cand), k=(l>>5)*8+j. B-frag: col=l&31 (query), same k.
// C/D: col=l&31, row=(reg&3)+8*(reg>>2)+4*(l>>5) [m74/m101 + R8-verified].
// v = -2 q.c + |c|^2; |q|^2 added in fp32 at loss time.
__global__ __launch_bounds__(256, 2) void k_min(const float* __restrict__ c,
                                                float* __restrict__ wpart) {
    __shared__ unsigned short A[16384];       // 32 tiles x 1024 B = 32 KB

    int blk = blockIdx.x;
    int cc  = blk & 3;            // candidate chunk (1024)
    int qb  = (blk >> 2) & 15;    // query block (256)
    int b   = blk >> 6;           // batch

    int t = threadIdx.x;
    int l = t & 63;
    int w = __builtin_amdgcn_readfirstlane(t >> 6);

    const float* cb = c + (size_t)b * N * 3;
    int C0  = cc << 10;
    int Q0w = (qb << 8) + (w << 6);           // this wave's first query (64 q)

    // ---- stage: thread t converts cands 4t..4t+3 (3 coalesced float4) ----
    {
        const float4* p = (const float4*)(cb + 3 * C0) + 3 * t;
        float4 c0 = p[0], c1 = p[1], c2 = p[2];
        float cx[4] = {c0.x, c0.w, c1.z, c2.y};
        float cy[4] = {c0.y, c1.x, c1.w, c2.z};
        float cz[4] = {c0.z, c1.y, c2.x, c2.w};
        #pragma unroll
        for (int j = 0; j < 4; ++j) {
            float x = cx[j], y = cy[j], z = cz[j];
            float m2x = -2.f * x, m2y = -2.f * y, m2z = -2.f * z;
            unsigned short Hx = f2bf(m2x), Hy = f2bf(m2y), Hz = f2bf(m2z);
            unsigned short Lx = f2bf(m2x - bf2f(Hx));
            unsigned short Ly = f2bf(m2y - bf2f(Hy));
            unsigned short Lz = f2bf(m2z - bf2f(Hz));
            float nc = fmaf(z, z, fmaf(y, y, x * x));
            unsigned short nh = f2bf(nc);
            unsigned short nl = f2bf(nc - bf2f(nh));
            int cl   = 4 * t + j;
            int base = ((cl >> 5) << 9) + ((cl & 31) << 3);
            *(bf16x8*)(A + base) =
                (bf16x8){(short)Hx, (short)Hy, (short)Hz, (short)Lx,
                         (short)Ly, (short)Lz, (short)Hx, (short)Hy};
            *(bf16x8*)(A + base + 256) =
                (bf16x8){(short)Hz, (short)nh, (short)nl, 0, 0, 0, 0, 0};
        }
    }

    // ---- build 2 query B-frags (held in VGPRs all loop) ----
    bf16x8 bf0, bf1;
    {
        int qn = l & 31;
        const float* pa = cb + 3 * (Q0w + qn);
        const float* pb = cb + 3 * (Q0w + 32 + qn);
        float ax = pa[0], ay = pa[1], az = pa[2];
        float bx = pb[0], by = pb[1], bz = pb[2];
        const short one = (short)0x3F80;      // bf16(1.0)
        if (l < 32) {                         // k-slots 0..7
            unsigned short hx = f2bf(ax), hy = f2bf(ay), hz = f2bf(az);
            unsigned short lx = f2bf(ax - bf2f(hx));
            unsigned short ly = f2bf(ay - bf2f(hy));
            bf0 = (bf16x8){(short)hx, (short)hy, (short)hz, (short)hx,
                           (short)hy, (short)hz, (short)lx, (short)ly};
            hx = f2bf(bx); hy = f2bf(by); hz = f2bf(bz);
            lx = f2bf(bx - bf2f(hx)); ly = f2bf(by - bf2f(hy));
            bf1 = (bf16x8){(short)hx, (short)hy, (short)hz, (short)hx,
                           (short)hy, (short)hz, (short)lx, (short)ly};
        } else {                              // k-slots 8..15
            unsigned short hz = f2bf(az);
            unsigned short lz = f2bf(az - bf2f(hz));
            bf0 = (bf16x8){(short)lz, one, one, 0, 0, 0, 0, 0};
            hz = f2bf(bz); lz = f2bf(bz - bf2f(hz));
            bf1 = (bf16x8){(short)lz, one, one, 0, 0, 0, 0, 0};
        }
    }

    // diag bookkeeping: per frag the diag tile is wave-uniform
    int rel0 = Q0w - C0;
    int dt0  = ((unsigned)rel0 < 1024u) ? (rel0 >> 5) : -1;
    int rel1 = rel0 + 32;
    int dt1  = ((unsigned)rel1 < 1024u) ? (rel1 >> 5) : -1;
    // self-hit: query col rq = l&31 lives at row rq -> lane half (rq>>2)&1
    bool sel  = (((l >> 2) & 1) == (l >> 5));
    int  rsel = (l & 3) | (((l & 31) >> 3) << 2);

    __syncthreads();

    const float INF = __uint_as_float(0x7F800000u);
    float mm0[8], mm1[8];
    #pragma unroll
    for (int i = 0; i < 8; ++i) { mm0[i] = INF; mm1[i] = INF; }
    f32x16 z16 = {0.f, 0.f, 0.f, 0.f, 0.f, 0.f, 0.f, 0.f,
                  0.f, 0.f, 0.f, 0.f, 0.f, 0.f, 0.f, 0.f};

    #pragma unroll 2
    for (int tile = 0; tile < 32; ++tile) {
        bf16x8 a = *(const bf16x8*)(A + (tile << 9) + l * 8);
        f32x16 d0 = __builtin_amdgcn_mfma_f32_32x32x16_bf16(a, bf0, z16, 0, 0, 0);
        if (tile == dt0) {
            #pragma unroll
            for (int i = 0; i < 16; ++i)
                d0[i] = (sel && rsel == i) ? INF : d0[i];
        }
        #pragma unroll
        for (int i = 0; i < 8; ++i)
            mm0[i] = fminf(fminf(mm0[i], d0[2 * i]), d0[2 * i + 1]);

        f32x16 d1 = __builtin_amdgcn_mfma_f32_32x32x16_bf16(a, bf1, z16, 0, 0, 0);
        if (tile == dt1) {
            #pragma unroll
            for (int i = 0; i < 16; ++i)
                d1[i] = (sel && rsel == i) ? INF : d1[i];
        }
        #pragma unroll
        for (int i = 0; i < 8; ++i)
            mm1[i] = fminf(fminf(mm1[i], d1[2 * i]), d1[2 * i + 1]);
    }

    // ---- fold 8 -> 1 per frag, then combine row-halves (xor 32) ----
    float M0 = fminf(fminf(fminf(mm0[0], mm0[1]), fminf(mm0[2], mm0[3])),
                     fminf(fminf(mm0[4], mm0[5]), fminf(mm0[6], mm0[7])));
    float M1 = fminf(fminf(fminf(mm1[0], mm1[1]), fminf(mm1[2], mm1[3])),
                     fminf(fminf(mm1[4], mm1[5]), fminf(mm1[6], mm1[7])));
    M0 = fminf(M0, __shfl_xor(M0, 32));
    M1 = fminf(M1, __shfl_xor(M1, 32));

    // lane l stores query Q0w + l (lanes<32 from frag0, >=32 from frag1)
    float val = (l < 32) ? M0 : M1;
    wpart[(size_t)((b << 12) + Q0w + l) * 4 + cc] = val;
}

// ---------------- loss stage 1: 128 block partials (no atomics) -------------
__global__ __launch_bounds__(256) void k_loss1(const float* __restrict__ c,
                                               const float* __restrict__ wpart,
                                               double* __restrict__ partials) {
    int t = threadIdx.x;
    int i = blockIdx.x * 256 + t;             // global node index
    float4 v = ((const float4*)wpart)[i];
    float m = fminf(fminf(v.x, v.y), fminf(v.z, v.w));

    float x = c[3 * i], y = c[3 * i + 1], z = c[3 * i + 2];
    float nrm = fmaf(z, z, fmaf(y, y, x * x));   // |q|^2 in fp32
    float d2 = fmaxf(m + nrm, 0.0f);
    float e  = sqrtf(d2) - 0.2f;
    double s = (double)(e * e);

    for (int off = 32; off; off >>= 1) s += __shfl_down(s, off);
    __shared__ double sh[4];
    int wv = t >> 6, l = t & 63;
    if (l == 0) sh[wv] = s;
    __syncthreads();
    if (t == 0) partials[blockIdx.x] = sh[0] + sh[1] + sh[2] + sh[3];
}

// ---------------- loss stage 2: fold 128 partials -> scalar -----------------
__global__ __launch_bounds__(128) void k_loss2(const double* __restrict__ partials,
                                               float* __restrict__ out) {
    int t = threadIdx.x;
    double s = partials[t];
    for (int off = 32; off; off >>= 1) s += __shfl_down(s, off);
    __shared__ double sh[2];
    if ((t & 63) == 0) sh[t >> 6] = s;
    __syncthreads();
    if (t == 0) out[0] = (float)((sh[0] + sh[1]) / (double)BN);
}

// ---------------- fallback (tiny workspace): fused single kernel ------------
__global__ __launch_bounds__(64) void k_single(const float* __restrict__ c,
                                               float* __restrict__ out) {
    __shared__ float sx[N], sy[N], sz[N];
    int blk = blockIdx.x;
    int qt  = blk & (N / 64 - 1);
    int b   = blk / (N / 64);
    const float* cb = c + (size_t)b * N * 3;
    int t = threadIdx.x;

    for (int k = t; k < N; k += 64) {
        sx[k] = cb[3 * k];
        sy[k] = cb[3 * k + 1];
        sz[k] = cb[3 * k + 2];
    }
    __syncthreads();

    int   qi = qt * 64 + t;
    float qx = sx[qi], qy = sy[qi], qz = sz[qi];
    const float INF = __uint_as_float(0x7F800000u);
    float m0 = INF, m1 = INF;
    for (int k = 0; k < N; k += 2) {
        float dx0 = qx - sx[k],     dy0 = qy - sy[k],     dz0 = qz - sz[k];
        float dx1 = qx - sx[k + 1], dy1 = qy - sy[k + 1], dz1 = qz - sz[k + 1];
        float d0 = dx0 * dx0 + dy0 * dy0 + dz0 * dz0;
        float d1 = dx1 * dx1 + dy1 * dy1 + dz1 * dz1;
        d0 = (k + 0 == qi) ? INF : d0;
        d1 = (k + 1 == qi) ? INF : d1;
        m0 = fminf(m0, d0);
        m1 = fminf(m1, d1);
    }
    float e = sqrtf(fminf(m0, m1)) - 0.2f;
    float v = e * e;
    for (int off = 32; off; off >>= 1) v += __shfl_down(v, off);
    if (t == 0) atomicAdd(out, v / (float)BN);
}

extern "C" void kernel_launch(void* const* d_in, const int* in_sizes, int n_in,
                              void* d_out, int out_size, void* d_ws, size_t ws_size,
                              hipStream_t stream) {
    const float* c   = (const float*)d_in[0];
    float*       out = (float*)d_out;

    const size_t off_part = (size_t)BN * 4 * sizeof(float);   // 524288
    const size_t need     = off_part + NBLK_LOSS * sizeof(double);
    if (ws_size >= need) {
        float*  wpart    = (float*)d_ws;
        double* partials = (double*)((char*)d_ws + off_part);
        k_min  <<<NBLK_MIN, 256, 0, stream>>>(c, wpart);
        k_loss1<<<NBLK_LOSS, 256, 0, stream>>>(c, wpart, partials);
        k_loss2<<<1, 128, 0, stream>>>(partials, out);
    } else {
        hipMemsetAsync(d_out, 0, sizeof(float), stream);
        k_single<<<B * (N / 64), 64, 0, stream>>>(c, out);
    }
}